// Round 1
// 609.379 us; speedup vs baseline: 1.0097x; 1.0097x over previous
//
#include <hip/hip_runtime.h>
#include <stdint.h>

#define N_NODES 100000
#define N_EDGES 1000000
#define DIM 256
#define SLAB 2048

typedef __attribute__((ext_vector_type(8))) short short8;          // bf16 MFMA frag (4 VGPR)
typedef __attribute__((ext_vector_type(8))) unsigned short u16x8;  // 16B row chunk
typedef __attribute__((ext_vector_type(4))) float f32x4;           // fp32 C/D frag

__device__ inline float b2f(unsigned short u) {
    union { unsigned int i; float f; } v; v.i = ((unsigned int)u) << 16; return v.f;
}
__device__ inline unsigned short f2b(float f) {   // round-to-nearest-even
    union { float f; unsigned int i; } v; v.f = f;
    unsigned int u = v.i;
    return (unsigned short)((u + 0x7FFFu + ((u >> 16) & 1u)) >> 16);
}

// ---------------- workspace layout (bytes) ----------------
// deg     u32 N        @ 0
// cursor  u32 N        @ 400000
// counter u32 1        @ 800000
// dinv    f32 N        @ 800256
// start   u32 N        @ 1200384
// col     i32 E        @ 1600512
// Wt1     bf16 256x256 @ 5600512   (n-major, k contiguous)
// Wt2     bf16 256x256 @ 5731584
// xs      bf16 N*256   @ 5862656    (dinv-prescaled features, layer input)
// z1s     bf16 N*256   @ 108262656  (dinv-prescaled layer-1 output)

__global__ void k_zero(uint32_t* __restrict__ p, int n) {
    int i = blockIdx.x * blockDim.x + threadIdx.x;
    int stride = gridDim.x * blockDim.x;
    for (; i < n; i += stride) p[i] = 0u;
}

__global__ void k_count(const int* __restrict__ dst, uint32_t* __restrict__ deg) {
    int e = blockIdx.x * blockDim.x + threadIdx.x;
    if (e < N_EDGES) {
        unsigned d = (unsigned)dst[e];
        if (d < N_NODES) atomicAdd(&deg[d], 1u);
    }
}

// Per-64-node-group exclusive prefix + one atomic base per group.
// KEY INVARIANT (used by k_fused): the col[] entries of nodes [64g, 64g+64)
// occupy ONE contiguous ascending range [start[64g], start[64g]+sum_deg).
__global__ void k_dinv_start(const uint32_t* __restrict__ deg,
                             float* __restrict__ dinv,
                             uint32_t* __restrict__ start,
                             uint32_t* __restrict__ counter) {
    int n = blockIdx.x * blockDim.x + threadIdx.x;
    int lane = threadIdx.x & 63;
    int d = (n < N_NODES) ? (int)deg[n] : 0;
    int v = d;
    #pragma unroll
    for (int off = 1; off < 64; off <<= 1) {
        int t = __shfl_up(v, off, 64);
        if (lane >= off) v += t;
    }
    int total = __shfl(v, 63, 64);
    int base = 0;
    if (lane == 63) base = (int)atomicAdd(counter, (uint32_t)total);
    base = __shfl(base, 63, 64);
    if (n < N_NODES) {
        start[n] = (uint32_t)(base + v - d);   // exclusive
        dinv[n]  = rsqrtf((float)(d + 1));     // +1 self-loop
    }
}

__global__ void k_fill(const int* __restrict__ src, const int* __restrict__ dst,
                       const uint32_t* __restrict__ start,
                       uint32_t* __restrict__ cursor, int* __restrict__ col) {
    int e = blockIdx.x * blockDim.x + threadIdx.x;
    if (e < N_EDGES) {
        unsigned d = (unsigned)dst[e];
        unsigned s = (unsigned)src[e];
        if (d < N_NODES && s < N_NODES) {
            uint32_t p = atomicAdd(&cursor[d], 1u);
            col[start[d] + p] = (int)s;
        }
    }
}

// W (k-major, [k][n] fp32) -> Wt (n-major, [n][k] bf16)
__global__ void k_pack_w(const float* __restrict__ W, unsigned short* __restrict__ Wt) {
    int n = blockIdx.x, k = threadIdx.x;
    Wt[n * 256 + k] = f2b(W[k * 256 + n]);
}

// xs[row] = bf16( dinv[row] * x[row] )
__global__ void k_cvt_x(const float* __restrict__ x, const float* __restrict__ dinv,
                        unsigned short* __restrict__ xs) {
    int i = blockIdx.x * 256 + threadIdx.x;   // float4 index
    int row = i >> 6;                          // 64 float4 per row
    float di = dinv[row];
    float4 v = ((const float4*)x)[i];
    ushort4 o;
    o.x = f2b(di * v.x); o.y = f2b(di * v.y); o.z = f2b(di * v.z); o.w = f2b(di * v.w);
    ((ushort4*)xs)[i] = o;
}

// Fused gather + GEMM per 64-node block (4 waves).
//
// Phase 1 (gather): each wave owns 16 nodes, processed as 8 half-wave PAIRS
// (lanes 0-31 = node A, 32-63 = node B, 16 B/lane -> one ushort8 load covers
// 2 rows, 4-deep unroll = 8 rows of 512 B in flight). Edge indices come from
// an LDS slab (contiguous per 64-group by k_dinv_start construction; global
// fallback if >SLAB). Result rows = bf16(dinv*(self+sum)) are packed straight
// into the XOR-swizzled LDS A-tile (linear 512 B row stride, 16B-chunk index
// ^= row&7 -> 2-way-max bank aliasing on both the ds_write and ds_read_b128).
//
// Phase 2 (GEMM, swapped operands): acc = mfma(Wt_frag, A_frag, acc) computes
// C^T in-register: D row (quad*4+r) = output COLUMN, D col (lane&15) = node.
// Each thread thus holds 4 consecutive output columns per fragment ->
// float4 (fp32 out) / ushort4 (bf16 z1s) vector stores: 16 stores/thread
// instead of 64 scalar dwords.
__global__ __launch_bounds__(256) void k_fused(
        const unsigned short* __restrict__ rows, const float* __restrict__ dinv,
        const uint32_t* __restrict__ start, const uint32_t* __restrict__ deg,
        const int* __restrict__ col, const unsigned short* __restrict__ Wt,
        const float* __restrict__ bias,
        unsigned short* __restrict__ Cb, float* __restrict__ Cf) {
    __shared__ __align__(16) unsigned short As[64 * 256];   // 32768 B, swizzled
    __shared__ int colS[SLAB];                              // 8192 B

    int tid = threadIdx.x;
    int w = tid >> 6, lane = tid & 63;
    int hl = lane & 31, half = lane >> 5;
    int rowBase = blockIdx.x * 64;

    // ---- stage this block's edge-index slab (contiguous range) ----
    int lastValid = rowBase + 63;
    if (lastValid >= N_NODES) lastValid = N_NODES - 1;
    uint32_t eBase = start[rowBase];
    uint32_t eCnt  = start[lastValid] + deg[lastValid] - eBase;
    uint32_t eLds  = eCnt < (uint32_t)SLAB ? eCnt : (uint32_t)SLAB;
    for (uint32_t i = (uint32_t)tid; i < eLds; i += 256u) colS[i] = col[eBase + i];
    __syncthreads();

    // ---- phase 1: gather 16 nodes/wave as 8 half-wave pairs ----
    const u16x8* r8 = (const u16x8*)rows;
    for (int t = 0; t < 8; ++t) {
        int nl   = w * 16 + t * 2 + half;     // local row 0..63
        int node = rowBase + nl;
        bool valid = node < N_NODES;
        uint32_t dg = valid ? deg[node]   : 0u;
        uint32_t st = valid ? start[node] : eBase;
        float    di = valid ? dinv[node]  : 0.f;
        uint32_t sL = st - eBase;
        bool inS = (sL + dg) <= eLds;

        float a[8];
        if (valid) {
            u16x8 sv = r8[(size_t)node * 32 + hl];   // self (prescaled)
            #pragma unroll
            for (int i = 0; i < 8; ++i) a[i] = b2f(sv[i]);
        } else {
            #pragma unroll
            for (int i = 0; i < 8; ++i) a[i] = 0.f;
        }

        uint32_t dgo   = __shfl(dg, lane ^ 32);
        uint32_t dgMax = dg > dgo ? dg : dgo;

        for (uint32_t j = 0; j < dgMax; j += 4) {
            u16x8 v0 = {0,0,0,0,0,0,0,0};
            u16x8 v1 = v0, v2 = v0, v3 = v0;
            if (j + 0 < dg) { int ix = inS ? colS[sL + j + 0] : col[st + j + 0]; v0 = r8[(size_t)ix * 32 + hl]; }
            if (j + 1 < dg) { int ix = inS ? colS[sL + j + 1] : col[st + j + 1]; v1 = r8[(size_t)ix * 32 + hl]; }
            if (j + 2 < dg) { int ix = inS ? colS[sL + j + 2] : col[st + j + 2]; v2 = r8[(size_t)ix * 32 + hl]; }
            if (j + 3 < dg) { int ix = inS ? colS[sL + j + 3] : col[st + j + 3]; v3 = r8[(size_t)ix * 32 + hl]; }
            #pragma unroll
            for (int i = 0; i < 8; ++i)
                a[i] += (b2f(v0[i]) + b2f(v1[i])) + (b2f(v2[i]) + b2f(v3[i]));
        }

        short8 o;
        #pragma unroll
        for (int i = 0; i < 8; ++i) o[i] = (short)f2b(di * a[i]);
        // swizzled write: logical chunk hl -> physical chunk hl ^ (row&7)
        *(short8*)((char*)As + nl * 512 + ((hl ^ (nl & 7)) << 4)) = o;
    }
    __syncthreads();

    // ---- phase 2: GEMM, swapped operands ----
    int m = lane & 15, quad = lane >> 4;

    f32x4 acc[4][4];
    #pragma unroll
    for (int mt = 0; mt < 4; ++mt)
        #pragma unroll
        for (int nt = 0; nt < 4; ++nt)
            acc[mt][nt] = (f32x4){0.f, 0.f, 0.f, 0.f};

    #pragma unroll
    for (int ks = 0; ks < 8; ++ks) {          // K = 8 steps x 32
        short8 wf[4], xf[4];
        #pragma unroll
        for (int nt = 0; nt < 4; ++nt)
            wf[nt] = *(const short8*)(Wt + (size_t)(w * 64 + nt * 16 + m) * 256 + ks * 32 + quad * 8);
        #pragma unroll
        for (int mt = 0; mt < 4; ++mt) {
            int rl = mt * 16 + m;
            int ch = (ks * 4 + quad) ^ (rl & 7);
            xf[mt] = *(const short8*)((const char*)As + rl * 512 + (ch << 4));
        }
        #pragma unroll
        for (int mt = 0; mt < 4; ++mt)
            #pragma unroll
            for (int nt = 0; nt < 4; ++nt)
                acc[mt][nt] = __builtin_amdgcn_mfma_f32_16x16x32_bf16(
                    wf[nt], xf[mt], acc[mt][nt], 0, 0, 0);
    }

    // epilogue: D row (quad*4+r) = output col, D col (lane&15) = node
    float4 bv[4];
    #pragma unroll
    for (int nt = 0; nt < 4; ++nt)
        bv[nt] = *(const float4*)(bias + w * 64 + nt * 16 + quad * 4);

    #pragma unroll
    for (int mt = 0; mt < 4; ++mt) {
        int node = rowBase + mt * 16 + m;
        if (node >= N_NODES) continue;
        if (Cf) {
            #pragma unroll
            for (int nt = 0; nt < 4; ++nt) {
                int c = w * 64 + nt * 16 + quad * 4;
                f32x4 v = acc[mt][nt];
                float4 o;
                o.x = fmaxf(v[0] + bv[nt].x, 0.f);
                o.y = fmaxf(v[1] + bv[nt].y, 0.f);
                o.z = fmaxf(v[2] + bv[nt].z, 0.f);
                o.w = fmaxf(v[3] + bv[nt].w, 0.f);
                *(float4*)(Cf + (size_t)node * 256 + c) = o;
            }
        } else {
            float di = dinv[node];
            #pragma unroll
            for (int nt = 0; nt < 4; ++nt) {
                int c = w * 64 + nt * 16 + quad * 4;
                f32x4 v = acc[mt][nt];
                ushort4 o;
                o.x = f2b(di * fmaxf(v[0] + bv[nt].x, 0.f));
                o.y = f2b(di * fmaxf(v[1] + bv[nt].y, 0.f));
                o.z = f2b(di * fmaxf(v[2] + bv[nt].z, 0.f));
                o.w = f2b(di * fmaxf(v[3] + bv[nt].w, 0.f));
                *(ushort4*)(Cb + (size_t)node * 256 + c) = o;
            }
        }
    }
}

extern "C" void kernel_launch(void* const* d_in, const int* in_sizes, int n_in,
                              void* d_out, int out_size, void* d_ws, size_t ws_size,
                              hipStream_t stream) {
    const int*   edge = (const int*)d_in[0];   // [2][E]: row0 = src, row1 = dst
    const float* x    = (const float*)d_in[1];
    const float* W1   = (const float*)d_in[2];
    const float* b1   = (const float*)d_in[3];
    const float* W2   = (const float*)d_in[4];
    const float* b2   = (const float*)d_in[5];
    float* out = (float*)d_out;

    char* ws = (char*)d_ws;
    uint32_t*       deg     = (uint32_t*)(ws + 0);
    uint32_t*       cursor  = (uint32_t*)(ws + 400000);
    uint32_t*       counter = (uint32_t*)(ws + 800000);
    float*          dinv    = (float*)   (ws + 800256);
    uint32_t*       start   = (uint32_t*)(ws + 1200384);
    int*            col     = (int*)     (ws + 1600512);
    unsigned short* Wt1     = (unsigned short*)(ws + 5600512);
    unsigned short* Wt2     = (unsigned short*)(ws + 5731584);
    unsigned short* xs      = (unsigned short*)(ws + 5862656);
    unsigned short* z1s     = (unsigned short*)(ws + 108262656ull);

    const int* src = edge;
    const int* dst = edge + N_EDGES;

    k_zero<<<256, 256, 0, stream>>>((uint32_t*)ws, 2 * N_NODES + 1);
    k_count<<<(N_EDGES + 255) / 256, 256, 0, stream>>>(dst, deg);
    k_dinv_start<<<(N_NODES + 255) / 256, 256, 0, stream>>>(deg, dinv, start, counter);
    k_fill<<<(N_EDGES + 255) / 256, 256, 0, stream>>>(src, dst, start, cursor, col);

    k_pack_w<<<256, 256, 0, stream>>>(W1, Wt1);
    k_pack_w<<<256, 256, 0, stream>>>(W2, Wt2);
    k_cvt_x<<<(N_NODES * DIM / 4) / 256, 256, 0, stream>>>(x, dinv, xs);

    // layer 1: fused gather+GEMM, epilogue writes dinv-prescaled z1s (bf16)
    k_fused<<<(N_NODES + 63) / 64, 256, 0, stream>>>(
        xs, dinv, start, deg, col, Wt1, b1, z1s, nullptr);
    // layer 2: fused gather+GEMM, epilogue writes fp32 output
    k_fused<<<(N_NODES + 63) / 64, 256, 0, stream>>>(
        z1s, dinv, start, deg, col, Wt2, b2, nullptr, out);
}

// Round 2
// 545.584 us; speedup vs baseline: 1.1277x; 1.1169x over previous
//
#include <hip/hip_runtime.h>
#include <stdint.h>

#define N_NODES 100000
#define N_EDGES 1000000
#define DIM 256
#define SLAB 1024

typedef __attribute__((ext_vector_type(8))) short short8;          // bf16 MFMA frag (4 VGPR)
typedef __attribute__((ext_vector_type(8))) unsigned short u16x8;  // 16B row chunk
typedef __attribute__((ext_vector_type(4))) float f32x4;           // fp32 C/D frag / NT store
typedef __attribute__((ext_vector_type(4))) unsigned short u16x4;  // 8B bf16 store

__device__ inline float b2f(unsigned short u) {
    union { unsigned int i; float f; } v; v.i = ((unsigned int)u) << 16; return v.f;
}
__device__ inline unsigned short f2b(float f) {   // round-to-nearest-even
    union { float f; unsigned int i; } v; v.f = f;
    unsigned int u = v.i;
    return (unsigned short)((u + 0x7FFFu + ((u >> 16) & 1u)) >> 16);
}

// ---------------- workspace layout (bytes) ----------------
// deg     u32 N        @ 0
// cursor  u32 N        @ 400000
// counter u32 1        @ 800000        (deg|cursor|counter contiguous -> one memset)
// dinv    f32 N        @ 800256
// start   u32 N        @ 1200384
// col     i32 E        @ 1600512
// Wt1     bf16 256x256 @ 5600512   (n-major, k contiguous)
// Wt2     bf16 256x256 @ 5731584
// xs      bf16 N*256   @ 5862656    (dinv-prescaled features, layer input)
// z1s     bf16 N*256   @ 108262656  (dinv-prescaled layer-1 output)

#define NB_COUNT 3907   // (1M+255)/256 edge blocks
#define NB_CVT   25000  // N*256/4 float4 elems / 256 threads

// fused: edge-degree count (blocks [0,3907)) + W1/W2 pack (blocks [3907,4419))
__global__ void k_pre1(const int* __restrict__ dst, uint32_t* __restrict__ deg,
                       const float* __restrict__ W1, const float* __restrict__ W2,
                       unsigned short* __restrict__ Wt1, unsigned short* __restrict__ Wt2) {
    int b = blockIdx.x, t = threadIdx.x;
    if (b < NB_COUNT) {
        int e = b * 256 + t;
        if (e < N_EDGES) {
            unsigned d = (unsigned)dst[e];
            if (d < N_NODES) atomicAdd(&deg[d], 1u);
        }
    } else if (b < NB_COUNT + 256) {
        int n = b - NB_COUNT;
        Wt1[n * 256 + t] = f2b(W1[t * 256 + n]);
    } else {
        int n = b - (NB_COUNT + 256);
        Wt2[n * 256 + t] = f2b(W2[t * 256 + n]);
    }
}

// Per-64-node-group exclusive prefix + one atomic base per group.
// KEY INVARIANT (used by k_fused): the col[] entries of nodes [64g, 64g+64)
// occupy ONE contiguous ascending range [start[64g], start[64g]+sum_deg).
__global__ void k_dinv_start(const uint32_t* __restrict__ deg,
                             float* __restrict__ dinv,
                             uint32_t* __restrict__ start,
                             uint32_t* __restrict__ counter) {
    int n = blockIdx.x * blockDim.x + threadIdx.x;
    int lane = threadIdx.x & 63;
    int d = (n < N_NODES) ? (int)deg[n] : 0;
    int v = d;
    #pragma unroll
    for (int off = 1; off < 64; off <<= 1) {
        int t = __shfl_up(v, off, 64);
        if (lane >= off) v += t;
    }
    int total = __shfl(v, 63, 64);
    int base = 0;
    if (lane == 63) base = (int)atomicAdd(counter, (uint32_t)total);
    base = __shfl(base, 63, 64);
    if (n < N_NODES) {
        start[n] = (uint32_t)(base + v - d);   // exclusive
        dinv[n]  = rsqrtf((float)(d + 1));     // +1 self-loop
    }
}

// fused: CSR fill (blocks [0,3907), latency/atomic-bound, dispatched first)
//      + x -> bf16 prescale (blocks [3907,28907), BW-bound, overlaps fill)
__global__ void k_pre2(const int* __restrict__ src, const int* __restrict__ dst,
                       const uint32_t* __restrict__ start,
                       uint32_t* __restrict__ cursor, int* __restrict__ col,
                       const float* __restrict__ x, const float* __restrict__ dinv,
                       unsigned short* __restrict__ xs) {
    int b = blockIdx.x, t = threadIdx.x;
    if (b < NB_COUNT) {
        int e = b * 256 + t;
        if (e < N_EDGES) {
            unsigned d = (unsigned)dst[e];
            unsigned s = (unsigned)src[e];
            if (d < N_NODES && s < N_NODES) {
                uint32_t p = atomicAdd(&cursor[d], 1u);
                col[start[d] + p] = (int)s;
            }
        }
    } else {
        int i = (b - NB_COUNT) * 256 + t;      // float4 index, exactly N*64
        int row = i >> 6;                       // 64 float4 per row
        float di = dinv[row];
        f32x4 v = __builtin_nontemporal_load((const f32x4*)x + i);  // read-once stream
        u16x4 o;
        o.x = f2b(di * v.x); o.y = f2b(di * v.y); o.z = f2b(di * v.z); o.w = f2b(di * v.w);
        *((u16x4*)xs + i) = o;                  // xs re-read by gather -> cacheable
    }
}

// Fused gather + GEMM per 64-node block (4 waves).
//
// Phase 1 (gather): each wave owns 16 nodes, processed as 8 half-wave PAIRS
// (lanes 0-31 = node A, 32-63 = node B, 16 B/lane -> one ushort8 load covers
// 2 rows, 4-deep unroll = 8 rows of 512 B in flight). Edge indices come from
// an LDS slab (contiguous per 64-group by k_dinv_start construction; global
// fallback if the block's range exceeds SLAB). Result rows are packed straight
// into the XOR-swizzled LDS A-tile.
// SLAB=1024 (avg block needs ~640): LDS = 32768+4096 = 36864 B -> 4 blocks/CU
// (vs 40960 -> 2-3), doubling resident waves and in-flight random row loads.
//
// Phase 2 (GEMM, swapped operands): acc = mfma(Wt_frag, A_frag, acc) computes
// C^T in-register: D row (quad*4+r) = output COLUMN, D col (lane&15) = node.
// -> float4 / ushort4 vector stores.
__global__ __launch_bounds__(256, 4) void k_fused(
        const unsigned short* __restrict__ rows, const float* __restrict__ dinv,
        const uint32_t* __restrict__ start, const uint32_t* __restrict__ deg,
        const int* __restrict__ col, const unsigned short* __restrict__ Wt,
        const float* __restrict__ bias,
        unsigned short* __restrict__ Cb, float* __restrict__ Cf) {
    __shared__ __align__(16) unsigned short As[64 * 256];   // 32768 B, swizzled
    __shared__ int colS[SLAB];                              // 4096 B

    int tid = threadIdx.x;
    int w = tid >> 6, lane = tid & 63;
    int hl = lane & 31, half = lane >> 5;
    int rowBase = blockIdx.x * 64;

    // ---- stage this block's edge-index slab (contiguous range) ----
    int lastValid = rowBase + 63;
    if (lastValid >= N_NODES) lastValid = N_NODES - 1;
    uint32_t eBase = start[rowBase];
    uint32_t eCnt  = start[lastValid] + deg[lastValid] - eBase;
    uint32_t eLds  = eCnt < (uint32_t)SLAB ? eCnt : (uint32_t)SLAB;
    for (uint32_t i = (uint32_t)tid; i < eLds; i += 256u) colS[i] = col[eBase + i];
    __syncthreads();

    // ---- phase 1: gather 16 nodes/wave as 8 half-wave pairs ----
    const u16x8* r8 = (const u16x8*)rows;
    for (int t = 0; t < 8; ++t) {
        int nl   = w * 16 + t * 2 + half;     // local row 0..63
        int node = rowBase + nl;
        bool valid = node < N_NODES;
        uint32_t dg = valid ? deg[node]   : 0u;
        uint32_t st = valid ? start[node] : eBase;
        float    di = valid ? dinv[node]  : 0.f;
        uint32_t sL = st - eBase;
        bool inS = (sL + dg) <= eLds;

        float a[8];
        if (valid) {
            u16x8 sv = r8[(size_t)node * 32 + hl];   // self (prescaled)
            #pragma unroll
            for (int i = 0; i < 8; ++i) a[i] = b2f(sv[i]);
        } else {
            #pragma unroll
            for (int i = 0; i < 8; ++i) a[i] = 0.f;
        }

        uint32_t dgo   = __shfl(dg, lane ^ 32);
        uint32_t dgMax = dg > dgo ? dg : dgo;

        for (uint32_t j = 0; j < dgMax; j += 4) {
            u16x8 v0 = {0,0,0,0,0,0,0,0};
            u16x8 v1 = v0, v2 = v0, v3 = v0;
            if (j + 0 < dg) { int ix = inS ? colS[sL + j + 0] : col[st + j + 0]; v0 = r8[(size_t)ix * 32 + hl]; }
            if (j + 1 < dg) { int ix = inS ? colS[sL + j + 1] : col[st + j + 1]; v1 = r8[(size_t)ix * 32 + hl]; }
            if (j + 2 < dg) { int ix = inS ? colS[sL + j + 2] : col[st + j + 2]; v2 = r8[(size_t)ix * 32 + hl]; }
            if (j + 3 < dg) { int ix = inS ? colS[sL + j + 3] : col[st + j + 3]; v3 = r8[(size_t)ix * 32 + hl]; }
            #pragma unroll
            for (int i = 0; i < 8; ++i)
                a[i] += (b2f(v0[i]) + b2f(v1[i])) + (b2f(v2[i]) + b2f(v3[i]));
        }

        short8 o;
        #pragma unroll
        for (int i = 0; i < 8; ++i) o[i] = (short)f2b(di * a[i]);
        // swizzled write: logical chunk hl -> physical chunk hl ^ (row&7)
        *(short8*)((char*)As + nl * 512 + ((hl ^ (nl & 7)) << 4)) = o;
    }
    __syncthreads();

    // ---- phase 2: GEMM, swapped operands ----
    int m = lane & 15, quad = lane >> 4;

    f32x4 acc[4][4];
    #pragma unroll
    for (int mt = 0; mt < 4; ++mt)
        #pragma unroll
        for (int nt = 0; nt < 4; ++nt)
            acc[mt][nt] = (f32x4){0.f, 0.f, 0.f, 0.f};

    #pragma unroll
    for (int ks = 0; ks < 8; ++ks) {          // K = 8 steps x 32
        short8 wf[4], xf[4];
        #pragma unroll
        for (int nt = 0; nt < 4; ++nt)
            wf[nt] = *(const short8*)(Wt + (size_t)(w * 64 + nt * 16 + m) * 256 + ks * 32 + quad * 8);
        #pragma unroll
        for (int mt = 0; mt < 4; ++mt) {
            int rl = mt * 16 + m;
            int ch = (ks * 4 + quad) ^ (rl & 7);
            xf[mt] = *(const short8*)((const char*)As + rl * 512 + (ch << 4));
        }
        #pragma unroll
        for (int mt = 0; mt < 4; ++mt)
            #pragma unroll
            for (int nt = 0; nt < 4; ++nt)
                acc[mt][nt] = __builtin_amdgcn_mfma_f32_16x16x32_bf16(
                    wf[nt], xf[mt], acc[mt][nt], 0, 0, 0);
    }

    // epilogue: D row (quad*4+r) = output col, D col (lane&15) = node
    float4 bv[4];
    #pragma unroll
    for (int nt = 0; nt < 4; ++nt)
        bv[nt] = *(const float4*)(bias + w * 64 + nt * 16 + quad * 4);

    #pragma unroll
    for (int mt = 0; mt < 4; ++mt) {
        int node = rowBase + mt * 16 + m;
        if (node >= N_NODES) continue;
        if (Cf) {
            #pragma unroll
            for (int nt = 0; nt < 4; ++nt) {
                int c = w * 64 + nt * 16 + quad * 4;
                f32x4 v = acc[mt][nt];
                f32x4 o;
                o.x = fmaxf(v[0] + bv[nt].x, 0.f);
                o.y = fmaxf(v[1] + bv[nt].y, 0.f);
                o.z = fmaxf(v[2] + bv[nt].z, 0.f);
                o.w = fmaxf(v[3] + bv[nt].w, 0.f);
                // final output: never re-read -> NT store, keep L2/L3 for gather rows
                __builtin_nontemporal_store(o, (f32x4*)(Cf + (size_t)node * 256 + c));
            }
        } else {
            float di = dinv[node];
            #pragma unroll
            for (int nt = 0; nt < 4; ++nt) {
                int c = w * 64 + nt * 16 + quad * 4;
                f32x4 v = acc[mt][nt];
                u16x4 o;
                o.x = f2b(di * fmaxf(v[0] + bv[nt].x, 0.f));
                o.y = f2b(di * fmaxf(v[1] + bv[nt].y, 0.f));
                o.z = f2b(di * fmaxf(v[2] + bv[nt].z, 0.f));
                o.w = f2b(di * fmaxf(v[3] + bv[nt].w, 0.f));
                *(u16x4*)(Cb + (size_t)node * 256 + c) = o;   // re-read by layer 2 -> cacheable
            }
        }
    }
}

extern "C" void kernel_launch(void* const* d_in, const int* in_sizes, int n_in,
                              void* d_out, int out_size, void* d_ws, size_t ws_size,
                              hipStream_t stream) {
    const int*   edge = (const int*)d_in[0];   // [2][E]: row0 = src, row1 = dst
    const float* x    = (const float*)d_in[1];
    const float* W1   = (const float*)d_in[2];
    const float* b1   = (const float*)d_in[3];
    const float* W2   = (const float*)d_in[4];
    const float* b2   = (const float*)d_in[5];
    float* out = (float*)d_out;

    char* ws = (char*)d_ws;
    uint32_t*       deg     = (uint32_t*)(ws + 0);
    uint32_t*       cursor  = (uint32_t*)(ws + 400000);
    float*          dinv    = (float*)   (ws + 800256);
    uint32_t*       counter = (uint32_t*)(ws + 800000);
    uint32_t*       start   = (uint32_t*)(ws + 1200384);
    int*            col     = (int*)     (ws + 1600512);
    unsigned short* Wt1     = (unsigned short*)(ws + 5600512);
    unsigned short* Wt2     = (unsigned short*)(ws + 5731584);
    unsigned short* xs      = (unsigned short*)(ws + 5862656);
    unsigned short* z1s     = (unsigned short*)(ws + 108262656ull);

    const int* src = edge;
    const int* dst = edge + N_EDGES;

    // deg | cursor | counter are contiguous: one async memset
    hipMemsetAsync(ws, 0, 800260, stream);

    k_pre1<<<NB_COUNT + 512, 256, 0, stream>>>(dst, deg, W1, W2, Wt1, Wt2);
    k_dinv_start<<<(N_NODES + 255) / 256, 256, 0, stream>>>(deg, dinv, start, counter);
    k_pre2<<<NB_COUNT + NB_CVT, 256, 0, stream>>>(src, dst, start, cursor, col, x, dinv, xs);

    // layer 1: fused gather+GEMM, epilogue writes dinv-prescaled z1s (bf16)
    k_fused<<<(N_NODES + 63) / 64, 256, 0, stream>>>(
        xs, dinv, start, deg, col, Wt1, b1, z1s, nullptr);
    // layer 2: fused gather+GEMM, epilogue writes fp32 output
    k_fused<<<(N_NODES + 63) / 64, 256, 0, stream>>>(
        z1s, dinv, start, deg, col, Wt2, b2, nullptr, out);
}